// Round 15
// baseline (4278.876 us; speedup 1.0000x reference)
//
#include <hip/hip_runtime.h>
#include <cstddef>

#define Bn  256
#define Tn  1024
#define Cn  128
#define Hn  256
#define WIN 24

#define NRG 16   // row groups (16 rows each)
#define NUG 8    // unit groups (32 units each)
#define RPB 16
#define UPB 32

#define AGENT __HIP_MEMORY_SCOPE_AGENT
#define RLX   __ATOMIC_RELAXED

typedef __attribute__((ext_vector_type(8))) short bf16x8;
typedef __attribute__((ext_vector_type(4))) float f32x4;
typedef __attribute__((ext_vector_type(4))) unsigned int u32x4;

#define MFMA(a, b, c) __builtin_amdgcn_mfma_f32_16x16x32_bf16((a), (b), (c), 0, 0, 0)

// counter-flag per (rg,ug): reaches 8*(t+1) when all 8 waves of that block
// have drained their h-publish stores for step t. Monotone; single address.
struct __align__(64) Ctr { int v; int pad[15]; };
__device__ Ctr g_ctr[NRG][NUG];
// h_in exchange: ONE packed dword per unit: (bf16hi << 16) | bf16lo,
// double-buffered by t parity.
__device__ unsigned g_hx_pk[2][Bn][Hn];

__device__ inline unsigned short f2bf(float f) {
    union { float f; unsigned u; } v; v.f = f;
    unsigned r = (v.u + 0x7FFF + ((v.u >> 16) & 1)) >> 16;   // RNE
    return (unsigned short)r;
}
__device__ inline float bf2f(unsigned short b) {
    union { unsigned u; float f; } v; v.u = (unsigned)b << 16;
    return v.f;
}
__device__ inline void split8(const float* s, bf16x8& hi, bf16x8& lo) {
    #pragma unroll
    for (int e = 0; e < 8; ++e) {
        unsigned short h = f2bf(s[e]);
        float r = s[e] - bf2f(h);
        hi[e] = (short)h;
        lo[e] = (short)f2bf(r);
    }
}
__device__ inline float fsigm(float x) {
    return __builtin_amdgcn_rcpf(1.f + exp2f(x * -1.442695041f));
}
__device__ inline float ftanh(float x) {
    return 1.f - 2.f * __builtin_amdgcn_rcpf(1.f + exp2f(x * 2.885390082f));
}

__global__ __launch_bounds__(256) void init_sync(const float* __restrict__ h0) {
    int i = blockIdx.x * 256 + threadIdx.x;       // 0 .. 65535
    int b = i >> 8, u = i & 255;
    float hv = h0[u];                              // h_in(0) = h0 (mask=0 at t=0)
    unsigned short hi = f2bf(hv);
    unsigned short lo = f2bf(hv - bf2f(hi));
    g_hx_pk[0][b][u] = ((unsigned)hi << 16) | lo;
    g_hx_pk[1][b][u] = 0;
    if (i < NRG * NUG) ((Ctr*)g_ctr)[i].v = 0;
}

__global__ __launch_bounds__(512, 1) void lstm_persist(
    const float* __restrict__ x,
    const float* __restrict__ W_ih, const float* __restrict__ W_hh,
    const float* __restrict__ b_ih, const float* __restrict__ b_hh,
    const float* __restrict__ W_skip, const float* __restrict__ b_skip,
    const float* __restrict__ h0, const float* __restrict__ c0,
    float* __restrict__ outp, float* __restrict__ hbuf, float* __restrict__ cbuf)
{
    __shared__ bf16x8 s_ga[2][12][64];     // [hi/lo][kstep 0..3 x, 4..11 h][lane]
    __shared__ bf16x8 s_sa[2][8][64];      // skip A-frags (h_{t-23})
    __shared__ float  s_part[8][64][4];    // per-wave gate D-frags
    __shared__ float  s_sk[4][2][64][4];   // skip partials [kpair][uh][lane][reg]
    __shared__ __align__(16) unsigned short s_hown_hi[16][32];   // own h_in planes
    __shared__ __align__(16) unsigned short s_hown_lo[16][32];
    __shared__ float  s_bias[128];
    __shared__ float  s_bskip[UPB];
    __shared__ float  s_pad[5600];         // pad: total >80KB -> 1 block/CU

    const int tid = threadIdx.x;
    if (tid == 0) ((volatile float*)s_pad)[0] = 0.f;

    // XCD swizzle (perf heuristic; r4-proven FETCH collapse)
    const int xcd = blockIdx.x & 7, slot = blockIdx.x >> 3;
    const int rg = (xcd << 1) | (slot >> 3), ug = slot & 7;
    const int row0 = rg * RPB, u0 = ug * UPB;

    const int w = tid >> 6, lane = tid & 63;
    const int g  = w >> 1, uh = w & 1;
    const int nl = lane & 15, kq = lane >> 4;
    const int sm = lane & 15;
    const int k0 = w * 32 + kq * 8;
    const bool own = (w == ug);
    const int cm = tid >> 5, cu = tid & 31;   // cell: wave w owns rows 2w,2w+1
    const int cli = ((cm >> 2) << 4) | (cu & 15), cr = cm & 3, cuh = cu >> 4;
    const int ksx2 = w - 4;
    const int mx2 = lane & 15, kqx2 = lane >> 4;

    // ---- once: B-operand weight fragments (r11-identical) ----
    bf16x8 whh_hi[8], whh_lo[8], wx_hi[4], wx_lo[4], ws_hi[2], ws_lo[2];
    {
        const int Rg = g * Hn + u0 + uh * 16 + nl;
        const float* wr = W_hh + (size_t)Rg * Hn;
        #pragma unroll
        for (int j = 0; j < 8; ++j) {
            float tmp[8];
            const int k = j * 32 + kq * 8;
            #pragma unroll
            for (int e = 0; e < 8; ++e) tmp[e] = wr[k + e];
            split8(tmp, whh_hi[j], whh_lo[j]);
        }
        const float* wr2 = W_ih + (size_t)Rg * Cn;
        #pragma unroll
        for (int j = 0; j < 4; ++j) {
            float tmp[8];
            const int k = j * 32 + kq * 8;
            #pragma unroll
            for (int e = 0; e < 8; ++e) tmp[e] = wr2[k + e];
            split8(tmp, wx_hi[j], wx_lo[j]);
        }
        const int Rs = u0 + uh * 16 + nl;
        const float* wr3 = W_skip + (size_t)Rs * Hn;
        #pragma unroll
        for (int j = 0; j < 2; ++j) {
            float tmp[8];
            const int k = ((w >> 1) * 2 + j) * 32 + kq * 8;
            #pragma unroll
            for (int e = 0; e < 8; ++e) tmp[e] = wr3[k + e];
            split8(tmp, ws_hi[j], ws_lo[j]);
        }
    }
    if (tid < 128) s_bias[tid] = b_ih[(tid >> 5) * Hn + u0 + (tid & 31)]
                               + b_hh[(tid >> 5) * Hn + u0 + (tid & 31)];
    if (tid < UPB) s_bskip[tid] = b_skip[u0 + tid];

    float c_reg = c0[u0 + cu];
    {
        float hv = h0[u0 + cu];
        unsigned short phi = f2bf(hv);
        s_hown_hi[cm][cu] = phi;
        s_hown_lo[cm][cu] = f2bf(hv - bf2f(phi));
    }
    // pre-loop: stage x(0) fragments (waves 0-3)
    if (tid < 256) {
        const int ksx = tid >> 6;
        const float* src = x + (size_t)(row0 + sm) * (Tn * Cn) + ksx * 32 + kq * 8;
        float tmp[8];
        #pragma unroll
        for (int e = 0; e < 8; ++e) tmp[e] = src[e];
        bf16x8 hi, lo; split8(tmp, hi, lo);
        s_ga[0][ksx][lane] = hi; s_ga[1][ksx][lane] = lo;
    }
    f32x4 ring_a = {0.f,0.f,0.f,0.f}, ring_b = {0.f,0.f,0.f,0.f};
    __syncthreads();

    for (int t = 0; t < Tn; ++t) {
        const bool do_ring = (t >= WIN - 1) && (t < Tn - 1);
        const bool nr      = (t >= WIN - 2) && (t < Tn - 2);
        const int  par     = t & 1;
        const int  need    = 8 * t;            // ctr threshold for step t

        // ================= PHASE A =================
        // A0: one FRESH counter sample per wave (r11 timing)
        int fv = 0x7fffffff;
        if (!own) fv = __hip_atomic_load(&g_ctr[rg][w].v, RLX, AGENT);

        // A1: stage ring octets (issued at B1 of t-1 -> ~1.5k cy in flight)
        if (do_ring) {
            asm volatile("s_waitcnt vmcnt(0)" : "+v"(ring_a), "+v"(ring_b) :: "memory");
            float rvv[8];
            #pragma unroll
            for (int e = 0; e < 4; ++e) { rvv[e] = ring_a[e]; rvv[4 + e] = ring_b[e]; }
            bf16x8 hi, lo; split8(rvv, hi, lo);
            s_sa[0][w][lane] = hi; s_sa[1][w][lane] = lo;
        }
        __syncthreads();   // (1)

        // A2: spec round 1 — producer already fully published
        const unsigned* pkp = &g_hx_pk[par][row0 + sm][k0];
        u32x4 pa = {0,0,0,0}, pb = {0,0,0,0};
        bool have = false;
        if (!own && fv >= need) {
            have = true;
            asm volatile("global_load_dwordx4 %0, %2, off sc0 sc1\n\t"
                         "global_load_dwordx4 %1, %2, off offset:16 sc0 sc1"
                         : "=&v"(pa), "=&v"(pb) : "v"(pkp) : "memory");
        }

        // A3: x-part MFMA (3 chains)
        f32x4 ac0 = {0.f,0.f,0.f,0.f}, ac1 = {0.f,0.f,0.f,0.f}, ac2 = {0.f,0.f,0.f,0.f};
        #pragma unroll
        for (int j = 0; j < 4; ++j) {
            bf16x8 ah = s_ga[0][j][lane], al = s_ga[1][j][lane];
            ac0 = MFMA(ah, wx_hi[j], ac0);
            ac1 = MFMA(ah, wx_lo[j], ac1);
            ac2 = MFMA(al, wx_hi[j], ac2);
        }
        // A4: skip MFMA (2 ksteps per wave) — in the flag-wait slack window
        if (do_ring) {
            f32x4 sk0 = {0.f,0.f,0.f,0.f}, sk1 = {0.f,0.f,0.f,0.f}, sk2 = {0.f,0.f,0.f,0.f};
            #pragma unroll
            for (int j = 0; j < 2; ++j) {
                const int ks = (w >> 1) * 2 + j;
                bf16x8 ah = s_sa[0][ks][lane], al = s_sa[1][ks][lane];
                sk0 = MFMA(ah, ws_hi[j], sk0);
                sk1 = MFMA(ah, ws_lo[j], sk1);
                sk2 = MFMA(al, ws_hi[j], sk2);
            }
            *(f32x4*)&s_sk[w >> 1][w & 1][lane][0] = sk0 + sk1 + sk2;
        }
        // A5: spec round 2
        if (!own && !have) {
            fv = __hip_atomic_load(&g_ctr[rg][w].v, RLX, AGENT);
            if (fv >= need) {
                have = true;
                asm volatile("global_load_dwordx4 %0, %2, off sc0 sc1\n\t"
                             "global_load_dwordx4 %1, %2, off offset:16 sc0 sc1"
                             : "=&v"(pa), "=&v"(pb) : "v"(pkp) : "memory");
            }
        }

        // ================= PHASE B =================
        // B1: uniform per-wave spin; load + unpack + stage h fragments
        if (!own) {
            while (fv < need)
                fv = __hip_atomic_load(&g_ctr[rg][w].v, RLX, AGENT);
            if (!have) {
                asm volatile("global_load_dwordx4 %0, %2, off sc0 sc1\n\t"
                             "global_load_dwordx4 %1, %2, off offset:16 sc0 sc1"
                             : "=&v"(pa), "=&v"(pb) : "v"(pkp) : "memory");
            }
            asm volatile("s_waitcnt vmcnt(0)" : "+v"(pa), "+v"(pb) :: "memory");
            union { bf16x8 v; unsigned d[4]; } Hh, Ll;
            #pragma unroll
            for (int e = 0; e < 2; ++e) {
                Hh.d[e]     = (pa[2*e+1] & 0xFFFF0000u) | (pa[2*e] >> 16);
                Ll.d[e]     = (pa[2*e+1] << 16)         | (pa[2*e] & 0xFFFFu);
                Hh.d[2 + e] = (pb[2*e+1] & 0xFFFF0000u) | (pb[2*e] >> 16);
                Ll.d[2 + e] = (pb[2*e+1] << 16)         | (pb[2*e] & 0xFFFFu);
            }
            s_ga[0][4 + w][lane] = Hh.v;
            s_ga[1][4 + w][lane] = Ll.v;
        } else {
            s_ga[0][4 + w][lane] = *(const bf16x8*)&s_hown_hi[sm][kq * 8];
            s_ga[1][4 + w][lane] = *(const bf16x8*)&s_hown_lo[sm][kq * 8];
        }
        // issue ring prefetch for t+1 — drained by B3's per-wave vmcnt (hidden)
        if (nr) {
            const float* rsrc = outp + (size_t)(row0 + sm) * (Tn * Hn)
                                     + (size_t)(t - (WIN - 2)) * Hn + k0;
            asm volatile("global_load_dwordx4 %0, %2, off sc0 sc1\n\t"
                         "global_load_dwordx4 %1, %2, off offset:16 sc0 sc1"
                         : "=&v"(ring_a), "=&v"(ring_b) : "v"(rsrc) : "memory");
        }
        // issue x(t+1) reg loads (waves 4-7); consumed at B4
        f32x4 xa, xb;
        const bool xst = (w >= 4) && (t + 1 < Tn);
        if (xst) {
            const float* xsrc = x + (size_t)(row0 + mx2) * (Tn * Cn)
                                  + (size_t)(t + 1) * Cn + ksx2 * 32 + kqx2 * 8;
            xa = *(const f32x4*)xsrc;
            xb = *(const f32x4*)(xsrc + 4);
        }
        __syncthreads();   // (3)

        // B2: h-part MFMA (8 ksteps, 3 chains), export D
        #pragma unroll
        for (int j = 0; j < 8; ++j) {
            bf16x8 ah = s_ga[0][4 + j][lane], al = s_ga[1][4 + j][lane];
            ac0 = MFMA(ah, whh_hi[j], ac0);
            ac1 = MFMA(ah, whh_lo[j], ac1);
            ac2 = MFMA(al, whh_hi[j], ac2);
        }
        *(f32x4*)&s_part[w][lane][0] = ac0 + ac1 + ac2;
        __syncthreads();   // (4)

        // B3: cell update + DIRECT register publish; wave w owns rows 2w,2w+1
        {
            float gv[4];
            #pragma unroll
            for (int g2 = 0; g2 < 4; ++g2)
                gv[g2] = s_part[g2 * 2 + cuh][cli][cr] + s_bias[g2 * 32 + cu];
            float si = fsigm(gv[0]);
            float sf = fsigm(gv[1]);
            float gt = ftanh(gv[2]);
            float so = fsigm(gv[3]);
            c_reg = sf * c_reg + si * gt;
            float hn = so * ftanh(c_reg);
            // outp store: wave covers 2 rows x 32 consecutive floats = 2x128B
            float* odst = &outp[(size_t)(row0 + cm) * (Tn * Hn) + (size_t)t * Hn + u0 + cu];
            asm volatile("global_store_dword %0, %1, off sc0 sc1"
                         :: "v"(odst), "v"(hn) : "memory");
            if (t < Tn - 1) {
                float hin = hn;
                if (do_ring) {
                    float sk = s_sk[0][cuh][cli][cr] + s_sk[1][cuh][cli][cr]
                             + s_sk[2][cuh][cli][cr] + s_sk[3][cuh][cli][cr];
                    hin += sk + s_bskip[cu];
                }
                unsigned short phi = f2bf(hin);
                unsigned short plo = f2bf(hin - bf2f(phi));
                s_hown_hi[cm][cu] = phi;   // own-slice path for next step
                s_hown_lo[cm][cu] = plo;
                unsigned pk = ((unsigned)phi << 16) | plo;
                unsigned* hdst = &g_hx_pk[par ^ 1][row0 + cm][u0 + cu];
                asm volatile("global_store_dword %0, %1, off sc0 sc1"
                             :: "v"(hdst), "v"(pk) : "memory");
            } else {
                hbuf[(size_t)(row0 + cm) * Hn + u0 + cu] = hn;
                cbuf[(size_t)(row0 + cm) * Hn + u0 + cu] = c_reg;
            }
        }

        // B4: x(t+1) LDS staging (waves 4-7) — LDS only, no global deps left
        if (xst) {
            float tmp[8];
            #pragma unroll
            for (int e = 0; e < 4; ++e) { tmp[e] = xa[e]; tmp[4 + e] = xb[e]; }
            bf16x8 hi, lo; split8(tmp, hi, lo);
            s_ga[0][ksx2][lane] = hi;
            s_ga[1][ksx2][lane] = lo;
        }

        // B5: per-wave drain of own publish stores, then counter post.
        // 8 waves drain in PARALLEL; flag reaches 8(t+1) when slowest wave acks.
        if (t < Tn - 1) {
            asm volatile("s_waitcnt vmcnt(0)" ::: "memory");
            if (lane == 0)
                __hip_atomic_fetch_add(&g_ctr[rg][ug].v, 1, RLX, AGENT);
        }
        // no tail barrier: next iteration's barrier (1) orders B4 LDS writes;
        // counter is monotone; outp ring-reads have 21 steps of slack
    }
}

extern "C" void kernel_launch(void* const* d_in, const int* in_sizes, int n_in,
                              void* d_out, int out_size, void* d_ws, size_t ws_size,
                              hipStream_t stream)
{
    const float* x      = (const float*)d_in[0];
    const float* W_ih   = (const float*)d_in[1];
    const float* W_hh   = (const float*)d_in[2];
    const float* b_ih   = (const float*)d_in[3];
    const float* b_hh   = (const float*)d_in[4];
    const float* W_skip = (const float*)d_in[5];
    const float* b_skip = (const float*)d_in[6];
    const float* h0     = (const float*)d_in[7];
    const float* c0     = (const float*)d_in[8];

    float* outp = (float*)d_out;
    float* hbuf = outp + (size_t)Bn * Tn * Hn;
    float* cbuf = hbuf + (size_t)Bn * Hn;

    init_sync<<<256, 256, 0, stream>>>(h0);
    lstm_persist<<<128, 512, 0, stream>>>(x, W_ih, W_hh, b_ih, b_hh,
                                          W_skip, b_skip, h0, c0, outp, hbuf, cbuf);
}

// Round 16
// 3175.982 us; speedup vs baseline: 1.3473x; 1.3473x over previous
//
#include <hip/hip_runtime.h>
#include <cstddef>

#define Bn  256
#define Tn  1024
#define Cn  128
#define Hn  256
#define WIN 24

#define NRG 16   // row groups (16 rows each)
#define NUG 8    // unit groups (32 units each)
#define RPB 16
#define UPB 32

#define AGENT __HIP_MEMORY_SCOPE_AGENT
#define RLX   __ATOMIC_RELAXED

typedef __attribute__((ext_vector_type(8))) short bf16x8;
typedef __attribute__((ext_vector_type(4))) float f32x4;

#define MFMA(a, b, c) __builtin_amdgcn_mfma_f32_16x16x32_bf16((a), (b), (c), 0, 0, 0)

struct __align__(64) Flag { int v; int pad[15]; };
__device__ Flag g_flag[NRG][NUG];
// h_in exchange as pre-split bf16 planes (r9-proven), double-buffered by parity
__device__ unsigned short g_hx_hi[2][Bn][Hn];
__device__ unsigned short g_hx_lo[2][Bn][Hn];

__device__ inline unsigned short f2bf(float f) {
    union { float f; unsigned u; } v; v.f = f;
    unsigned r = (v.u + 0x7FFF + ((v.u >> 16) & 1)) >> 16;   // RNE
    return (unsigned short)r;
}
__device__ inline float bf2f(unsigned short b) {
    union { unsigned u; float f; } v; v.u = (unsigned)b << 16;
    return v.f;
}
__device__ inline void split8(const float* s, bf16x8& hi, bf16x8& lo) {
    #pragma unroll
    for (int e = 0; e < 8; ++e) {
        unsigned short h = f2bf(s[e]);
        float r = s[e] - bf2f(h);
        hi[e] = (short)h;
        lo[e] = (short)f2bf(r);
    }
}
__device__ inline float fsigm(float x) {
    return __builtin_amdgcn_rcpf(1.f + exp2f(x * -1.442695041f));
}
__device__ inline float ftanh(float x) {
    return 1.f - 2.f * __builtin_amdgcn_rcpf(1.f + exp2f(x * 2.885390082f));
}

__global__ __launch_bounds__(256) void init_sync(const float* __restrict__ h0) {
    int i = blockIdx.x * 256 + threadIdx.x;       // 0 .. 65535
    int b = i >> 8, u = i & 255;
    float hv = h0[u];                              // h_in(0) = h0 (mask=0 at t=0)
    unsigned short hi = f2bf(hv);
    g_hx_hi[0][b][u] = hi;
    g_hx_lo[0][b][u] = f2bf(hv - bf2f(hi));
    g_hx_hi[1][b][u] = 0;
    g_hx_lo[1][b][u] = 0;
    if (i < NRG * NUG) ((Flag*)g_flag)[i].v = 0;
}

__global__ __launch_bounds__(512, 1) void lstm_persist(
    const float* __restrict__ x,
    const float* __restrict__ W_ih, const float* __restrict__ W_hh,
    const float* __restrict__ b_ih, const float* __restrict__ b_hh,
    const float* __restrict__ W_skip, const float* __restrict__ b_skip,
    const float* __restrict__ h0, const float* __restrict__ c0,
    float* __restrict__ outp, float* __restrict__ hbuf, float* __restrict__ cbuf)
{
    __shared__ bf16x8 s_ga[2][12][64];     // [hi/lo][kstep 0..3 x, 4..11 h][lane]
    __shared__ bf16x8 s_sa[2][8][64];      // skip A-frags (h_{t-23})
    __shared__ float  s_part[8][64][4];    // per-wave gate D-frags
    __shared__ float  s_sk[4][2][64][4];   // skip partials [kpair][uh][lane][reg]
    __shared__ __align__(16) unsigned short s_hown_hi[16][32];
    __shared__ __align__(16) unsigned short s_hown_lo[16][32];
    __shared__ float  s_hout[16][32];
    __shared__ float  s_bias[128];
    __shared__ float  s_bskip[UPB];
    __shared__ float  s_pad[5000];         // pad: total >80KB -> 1 block/CU

    const int tid = threadIdx.x;
    if (tid == 0) ((volatile float*)s_pad)[0] = 0.f;

    // XCD swizzle: each rg's 8 blocks on one XCD (x L2-dedup, r4-proven)
    const int xcd = blockIdx.x & 7, slot = blockIdx.x >> 3;   // slot 0..15
    const int rg = (xcd << 1) | (slot >> 3), ug = slot & 7;
    const int row0 = rg * RPB, u0 = ug * UPB;

    const int w = tid >> 6, lane = tid & 63;
    const int g  = w >> 1, uh = w & 1;        // gate tile (g, unit-half)
    const int nl = lane & 15, kq = lane >> 4;
    const int sm = lane & 15;                 // staged row
    const int k0 = w * 32 + kq * 8;           // staged unit-octet base (0..255)
    const bool own = (w == ug);               // wave w stages units of peer ug=w
    // cell mapping: one (row, unit) per thread
    const int cm = tid >> 5, cu = tid & 31;
    const int cli = ((cm >> 2) << 4) | (cu & 15), cr = cm & 3, cuh = cu >> 4;
    // x(t+1) staging role (waves 4-7)
    const int ksx2 = w - 4;
    const int mx2 = lane & 15, kqx2 = lane >> 4;

    // ---- once: B-operand weight fragments (full K per wave) ----
    bf16x8 whh_hi[8], whh_lo[8], wx_hi[4], wx_lo[4], ws_hi[2], ws_lo[2];
    {
        const int Rg = g * Hn + u0 + uh * 16 + nl;        // gate-row
        const float* wr = W_hh + (size_t)Rg * Hn;
        #pragma unroll
        for (int j = 0; j < 8; ++j) {
            float tmp[8];
            const int k = j * 32 + kq * 8;
            #pragma unroll
            for (int e = 0; e < 8; ++e) tmp[e] = wr[k + e];
            split8(tmp, whh_hi[j], whh_lo[j]);
        }
        const float* wr2 = W_ih + (size_t)Rg * Cn;
        #pragma unroll
        for (int j = 0; j < 4; ++j) {
            float tmp[8];
            const int k = j * 32 + kq * 8;
            #pragma unroll
            for (int e = 0; e < 8; ++e) tmp[e] = wr2[k + e];
            split8(tmp, wx_hi[j], wx_lo[j]);
        }
        const int Rs = u0 + uh * 16 + nl;                 // skip output unit row
        const float* wr3 = W_skip + (size_t)Rs * Hn;
        #pragma unroll
        for (int j = 0; j < 2; ++j) {
            float tmp[8];
            const int k = ((w >> 1) * 2 + j) * 32 + kq * 8;
            #pragma unroll
            for (int e = 0; e < 8; ++e) tmp[e] = wr3[k + e];
            split8(tmp, ws_hi[j], ws_lo[j]);
        }
    }
    if (tid < 128) s_bias[tid] = b_ih[(tid >> 5) * Hn + u0 + (tid & 31)]
                               + b_hh[(tid >> 5) * Hn + u0 + (tid & 31)];
    if (tid < UPB) s_bskip[tid] = b_skip[u0 + tid];

    float c_reg = c0[u0 + cu];
    {
        float hv = h0[u0 + cu];
        unsigned short phi = f2bf(hv);
        s_hown_hi[cm][cu] = phi;
        s_hown_lo[cm][cu] = f2bf(hv - bf2f(phi));
    }
    // pre-loop: stage x(0) fragments (waves 0-3)
    if (tid < 256) {
        const int ksx = tid >> 6;
        const float* src = x + (size_t)(row0 + sm) * (Tn * Cn) + ksx * 32 + kq * 8;
        float tmp[8];
        #pragma unroll
        for (int e = 0; e < 8; ++e) tmp[e] = src[e];
        bf16x8 hi, lo; split8(tmp, hi, lo);
        s_ga[0][ksx][lane] = hi; s_ga[1][ksx][lane] = lo;
    }
    f32x4 ring_a = {0.f,0.f,0.f,0.f}, ring_b = {0.f,0.f,0.f,0.f};
    __syncthreads();

    for (int t = 0; t < Tn; ++t) {
        const bool do_ring = (t >= WIN - 1) && (t < Tn - 1);
        const bool nr      = (t >= WIN - 2) && (t < Tn - 2);
        const int  par     = t & 1;

        // ================= PHASE A =================
        // A0: one flag sample per wave (uniform address -> 1 transaction)
        int fv = 0x7fffffff;
        if (!own) fv = __hip_atomic_load(&g_flag[rg][w].v, RLX, AGENT);

        // A1: stage ring octets (loaded at tail of t-1) into s_sa
        if (do_ring) {
            asm volatile("s_waitcnt vmcnt(0)" : "+v"(ring_a), "+v"(ring_b) :: "memory");
            float rvv[8];
            #pragma unroll
            for (int e = 0; e < 4; ++e) { rvv[e] = ring_a[e]; rvv[4 + e] = ring_b[e]; }
            bf16x8 hi, lo; split8(rvv, hi, lo);
            s_sa[0][w][lane] = hi; s_sa[1][w][lane] = lo;
        }
        __syncthreads();   // (1)

        // A2: spec round 1 — producer already published
        const unsigned short* hip_ = &g_hx_hi[par][row0 + sm][k0];
        const unsigned short* lop_ = &g_hx_lo[par][row0 + sm][k0];
        bf16x8 ha, hb;
        bool have = false;
        if (!own && fv >= t) {
            have = true;
            asm volatile("global_load_dwordx4 %0, %2, off sc0 sc1\n\t"
                         "global_load_dwordx4 %1, %3, off sc0 sc1"
                         : "=&v"(ha), "=&v"(hb) : "v"(hip_), "v"(lop_) : "memory");
        }

        // A3: x-part MFMA (full K-x per wave, 3 chains)
        f32x4 ac0 = {0.f,0.f,0.f,0.f}, ac1 = {0.f,0.f,0.f,0.f}, ac2 = {0.f,0.f,0.f,0.f};
        #pragma unroll
        for (int j = 0; j < 4; ++j) {
            bf16x8 ah = s_ga[0][j][lane], al = s_ga[1][j][lane];
            ac0 = MFMA(ah, wx_hi[j], ac0);
            ac1 = MFMA(ah, wx_lo[j], ac1);
            ac2 = MFMA(al, wx_hi[j], ac2);
        }
        // A4: skip MFMA (2 ksteps per wave)
        if (do_ring) {
            f32x4 sk0 = {0.f,0.f,0.f,0.f}, sk1 = {0.f,0.f,0.f,0.f}, sk2 = {0.f,0.f,0.f,0.f};
            #pragma unroll
            for (int j = 0; j < 2; ++j) {
                const int ks = (w >> 1) * 2 + j;
                bf16x8 ah = s_sa[0][ks][lane], al = s_sa[1][ks][lane];
                sk0 = MFMA(ah, ws_hi[j], sk0);
                sk1 = MFMA(ah, ws_lo[j], sk1);
                sk2 = MFMA(al, ws_hi[j], sk2);
            }
            *(f32x4*)&s_sk[w >> 1][w & 1][lane][0] = sk0 + sk1 + sk2;
        }
        // A5: spec round 2
        if (!own && !have) {
            fv = __hip_atomic_load(&g_flag[rg][w].v, RLX, AGENT);
            if (fv >= t) {
                have = true;
                asm volatile("global_load_dwordx4 %0, %2, off sc0 sc1\n\t"
                             "global_load_dwordx4 %1, %3, off sc0 sc1"
                             : "=&v"(ha), "=&v"(hb) : "v"(hip_), "v"(lop_) : "memory");
            }
        }

        // ================= PHASE B =================
        // B1: uniform per-wave spin on the ONE producer flag; then load + stage
        if (!own) {
            while (fv < t)
                fv = __hip_atomic_load(&g_flag[rg][w].v, RLX, AGENT);
            if (!have) {
                asm volatile("global_load_dwordx4 %0, %2, off sc0 sc1\n\t"
                             "global_load_dwordx4 %1, %3, off sc0 sc1"
                             : "=&v"(ha), "=&v"(hb) : "v"(hip_), "v"(lop_) : "memory");
            }
            asm volatile("s_waitcnt vmcnt(0)" : "+v"(ha), "+v"(hb) :: "memory");
            s_ga[0][4 + w][lane] = ha;
            s_ga[1][4 + w][lane] = hb;
        } else {
            s_ga[0][4 + w][lane] = *(const bf16x8*)&s_hown_hi[sm][kq * 8];
            s_ga[1][4 + w][lane] = *(const bf16x8*)&s_hown_lo[sm][kq * 8];
        }
        // issue x(t+1) loads (waves 4-7); consumed at B6 window
        f32x4 xa, xb;
        const bool xst = (w >= 4) && (t + 1 < Tn);
        if (xst) {
            const float* xsrc = x + (size_t)(row0 + mx2) * (Tn * Cn)
                                  + (size_t)(t + 1) * Cn + ksx2 * 32 + kqx2 * 8;
            xa = *(const f32x4*)xsrc;
            xb = *(const f32x4*)(xsrc + 4);
        }
        __syncthreads();   // (3)

        // B2: h-part MFMA (8 ksteps, 3 chains), export D
        #pragma unroll
        for (int j = 0; j < 8; ++j) {
            bf16x8 ah = s_ga[0][4 + j][lane], al = s_ga[1][4 + j][lane];
            ac0 = MFMA(ah, whh_hi[j], ac0);
            ac1 = MFMA(ah, whh_lo[j], ac1);
            ac2 = MFMA(al, whh_hi[j], ac2);
        }
        *(f32x4*)&s_part[w][lane][0] = ac0 + ac1 + ac2;
        __syncthreads();   // (4)

        // B3: cell update — every thread owns one (row cm, unit cu)
        {
            float gv[4];
            #pragma unroll
            for (int g2 = 0; g2 < 4; ++g2)
                gv[g2] = s_part[g2 * 2 + cuh][cli][cr] + s_bias[g2 * 32 + cu];
            float si = fsigm(gv[0]);
            float sf = fsigm(gv[1]);
            float gt = ftanh(gv[2]);
            float so = fsigm(gv[3]);
            c_reg = sf * c_reg + si * gt;
            float hn = so * ftanh(c_reg);
            s_hout[cm][cu] = hn;
            if (t < Tn - 1) {
                float hin = hn;
                if (do_ring) {
                    float sk = s_sk[0][cuh][cli][cr] + s_sk[1][cuh][cli][cr]
                             + s_sk[2][cuh][cli][cr] + s_sk[3][cuh][cli][cr];
                    hin += sk + s_bskip[cu];
                }
                unsigned short phi = f2bf(hin);
                s_hown_hi[cm][cu] = phi;
                s_hown_lo[cm][cu] = f2bf(hin - bf2f(phi));
            } else {
                hbuf[(size_t)(row0 + cm) * Hn + u0 + cu] = hn;
                cbuf[(size_t)(row0 + cm) * Hn + u0 + cu] = c_reg;
            }
        }
        __syncthreads();   // (5)

        // B4: batched 16B publishes (waves 0-3) || x(t+1) LDS staging (waves 4-7)
        if (tid < 64) {
            if (t < Tn - 1) {
                const int r8 = tid >> 2, q = tid & 3;
                f32x4 v = *(const f32x4*)&s_hown_hi[r8][q * 8];
                unsigned short* dst = &g_hx_hi[par ^ 1][row0 + r8][u0 + q * 8];
                asm volatile("global_store_dwordx4 %0, %1, off sc0 sc1"
                             :: "v"(dst), "v"(v) : "memory");
            }
        } else if (tid < 128) {
            if (t < Tn - 1) {
                const int r8 = (tid - 64) >> 2, q = tid & 3;
                f32x4 v = *(const f32x4*)&s_hown_lo[r8][q * 8];
                unsigned short* dst = &g_hx_lo[par ^ 1][row0 + r8][u0 + q * 8];
                asm volatile("global_store_dwordx4 %0, %1, off sc0 sc1"
                             :: "v"(dst), "v"(v) : "memory");
            }
        } else if (tid < 256) {
            const int i = tid - 128, r8 = i >> 3, q = i & 7;
            f32x4 v = *(const f32x4*)&s_hout[r8][q * 4];
            float* dst = &outp[(size_t)(row0 + r8) * (Tn * Hn) + (size_t)t * Hn + u0 + q * 4];
            asm volatile("global_store_dwordx4 %0, %1, off sc0 sc1"
                         :: "v"(dst), "v"(v) : "memory");
        } else if (xst) {
            float tmp[8];
            #pragma unroll
            for (int e = 0; e < 4; ++e) { tmp[e] = xa[e]; tmp[4 + e] = xb[e]; }
            bf16x8 hi, lo; split8(tmp, hi, lo);
            s_ga[0][ksx2][lane] = hi;
            s_ga[1][ksx2][lane] = lo;
        }

        // B5: drain publishes, then release our single flag
        asm volatile("s_waitcnt vmcnt(0)" ::: "memory");
        __syncthreads();   // (6)
        if (t < Tn - 1 && tid == 0)
            __hip_atomic_store(&g_flag[rg][ug].v, t + 1, RLX, AGENT);

        // tail: issue ring prefetch for t+1 (h(t-22)); in flight across boundary
        if (nr) {
            const float* rsrc = outp + (size_t)(row0 + sm) * (Tn * Hn)
                                     + (size_t)(t - (WIN - 2)) * Hn + k0;
            asm volatile("global_load_dwordx4 %0, %2, off sc0 sc1\n\t"
                         "global_load_dwordx4 %1, %2, off offset:16 sc0 sc1"
                         : "=&v"(ring_a), "=&v"(ring_b) : "v"(rsrc) : "memory");
        }
    }
}

extern "C" void kernel_launch(void* const* d_in, const int* in_sizes, int n_in,
                              void* d_out, int out_size, void* d_ws, size_t ws_size,
                              hipStream_t stream)
{
    const float* x      = (const float*)d_in[0];
    const float* W_ih   = (const float*)d_in[1];
    const float* W_hh   = (const float*)d_in[2];
    const float* b_ih   = (const float*)d_in[3];
    const float* b_hh   = (const float*)d_in[4];
    const float* W_skip = (const float*)d_in[5];
    const float* b_skip = (const float*)d_in[6];
    const float* h0     = (const float*)d_in[7];
    const float* c0     = (const float*)d_in[8];

    float* outp = (float*)d_out;
    float* hbuf = outp + (size_t)Bn * Tn * Hn;
    float* cbuf = hbuf + (size_t)Bn * Hn;

    init_sync<<<256, 256, 0, stream>>>(h0);
    lstm_persist<<<128, 512, 0, stream>>>(x, W_ih, W_hh, b_ih, b_hh,
                                          W_skip, b_skip, h0, c0, outp, hbuf, cbuf);
}